// Round 18
// baseline (106.836 us; speedup 1.0000x reference)
//
#include <hip/hip_runtime.h>
#include <hip/hip_bf16.h>

typedef short short8 __attribute__((ext_vector_type(8)));
typedef short short4_t __attribute__((ext_vector_type(4)));
typedef float floatx4 __attribute__((ext_vector_type(4)));
typedef unsigned short ushort_t;
typedef unsigned int uint32;

#define H 320
#define W 320
#define CG 16
#define NCH 64
#define HW (H * W)
#define CGP 20       // ushorts per LDS col (40B): conflict-free frag reads (measured 0)
#define SW 80        // strip width (4 strips): LDS 27.8KB -> 5 blocks/CU

__device__ __forceinline__ ushort_t f2bf(float f) {
  unsigned u = __float_as_uint(f);
  return (ushort_t)((u + 0x7FFFu + ((u >> 16) & 1u)) >> 16);  // RNE (weights only)
}

// LDS-only barrier: does NOT drain vmcnt -> global loads/stores stay in flight.
__device__ __forceinline__ void barrier_lgkm() {
  asm volatile("s_waitcnt lgkmcnt(0)" ::: "memory");
  __builtin_amdgcn_s_barrier();
}

// r18 = r17 body (swapped MFMA + nt dwordx4 store + ring-6 + balanced XCD map)
// at quarter-width strips (SW=80) and no LDS weight table (per-wave register
// gather) -> LDS 52->27.8 KB -> 5 blocks/CU (20 waves/CU, was 12).
template<int G>
__device__ __forceinline__ void conv_group(
    const float* __restrict__ x, const float* __restrict__ wgt,
    const float* __restrict__ bias, float* __restrict__ out,
    ushort_t* tile, int b, int j) {
  constexpr int DIL   = (G == 0) ? 1 : (G == 1) ? 6 : (G == 2) ? 12 : 18;
  constexpr int KOFF  = DIL & 1;
  constexpr int SHIFT = DIL + KOFF;              // lds col c <-> global col wb + c - SHIFT
  constexpr int WH    = (SW + 2 * DIL + KOFF + 1) & ~1;  // 84/92/104/116
  constexpr int NP    = 2;                       // ceil(WH/64)
  constexpr int RPW   = (H + DIL - 1) / DIL;
  constexpr int Q     = (RPW + 3) / 4;           // 80/14/7/5 tasks per walk
  constexpr int CPW   = (G == 0) ? 12 : (G == 1) ? 2 : 1;
  constexpr int L     = (Q + CPW - 1) / CPW;     // 7/7/7/5 tasks per chunk

  const int tid = threadIdx.x;
  const int lane = tid & 63;
  const int wv   = tid >> 6;
  const int z = lane >> 4, icq = z & 1, pxl = lane & 15, zh = z >> 1;

  // ---- per-wave weight fragments: register gather (no LDS table/syncs) ----
  short8 aw[5];
#pragma unroll
  for (int t = 0; t < 5; ++t) {
    const int tp = 2 * t + zh;                   // k-octet map: tap=2t+(z>>1)
#pragma unroll
    for (int jj = 0; jj < 8; ++jj) {
      float v = 0.f;
      if (tp < 9) v = wgt[((size_t)(G * CG + pxl) * CG + icq * 8 + jj) * 9 + tp];
      aw[t][jj] = (short)f2bf(v);
    }
  }
  const float bb = bias[G * CG + pxl];           // oc = lane&15 in swapped layout

  // ---- decode group-local j -> (chunk, r, strip); b = XCD/batch ----
  const int chunk = j % CPW;
  const int t1 = j / CPW;
  const int r  = t1 % DIL;
  const int wb = (t1 / DIL) * SW;                // strip in {0..3}
  const int q0 = chunk * L;
  const int qend = (q0 + L < Q) ? q0 + L : Q;

  // ---- staging constants: thread = (col = lane, ch-quad = wv) ----
  bool zm[NP]; bool inb[NP]; int gofs[NP];
#pragma unroll
  for (int p = 0; p < NP; ++p) {
    const int c = 64 * p + lane;
    inb[p] = (c < WH);
    const int gc = wb + c - SHIFT;
    zm[p] = inb[p] & (gc >= 0) & (gc < W);
    gofs[p] = gc < 0 ? 0 : (gc >= W ? W - 1 : gc);
  }
  const float* chb = x + (size_t)(b * NCH + G * CG + 4 * wv) * HW;

  auto LOADR = [&](int rho, float (&rg)[NP][4]) {
    const int yy = rho * DIL + r;
    const int yyc = yy < 0 ? 0 : (yy >= H ? H - 1 : yy);
    const float* rp = chb + (size_t)yyc * W;
#pragma unroll
    for (int p = 0; p < NP; ++p)
#pragma unroll
      for (int k = 0; k < 4; ++k)
        rg[p][k] = rp[(size_t)k * HW + gofs[p]];   // 256B coalesced per inst
  };

  auto CVTR = [&](int rho, int slot, float (&rg)[NP][4]) {
    const int yy = rho * DIL + r;
    const bool rv = (yy >= 0) & (yy < H);
#pragma unroll
    for (int p = 0; p < NP; ++p) {
      const bool m = rv & zm[p];
      const __hip_bfloat162 h01 = __float22bfloat162_rn(make_float2(rg[p][0], rg[p][1]));
      const __hip_bfloat162 h23 = __float22bfloat162_rn(make_float2(rg[p][2], rg[p][3]));
      uint2 pk;
      pk.x = m ? *(const uint32*)&h01 : 0u;
      pk.y = m ? *(const uint32*)&h23 : 0u;
      if (inb[p]) {
        const int c = 64 * p + lane;
        *(uint2*)&tile[(size_t)(slot * WH + c) * CGP + wv * 4] = pk;  // ds_write_b64
      }
    }
  };

  auto COMPUTE = [&](int q, int m6) {
    const int y = (4 * q + wv) * DIL + r;
    if (y >= H) return;
    // swapped C/D: lane&15 = oc, regs = px {4z..4z+3}
    float* outb = out + (size_t)(b * NCH + G * CG + pxl) * HW + (size_t)y * W + wb + 4 * z;
    const ushort_t* rowp[5];                 // statically indexed (unrolled t)
#pragma unroll
    for (int t = 0; t < 5; ++t) {
      const int tp = 2 * t + zh;
      const int ky = tp < 9 ? tp / 3 : 0;
      const int kx = tp < 9 ? tp - ky * 3 : 0;
      int s = m6 + wv + ky; s -= (s >= 6) ? 6 : 0;   // slot of row j = wv+ky
      rowp[t] = tile + (size_t)s * (WH * CGP) + (size_t)(pxl + kx * DIL + KOFF) * CGP + icq * 8;
    }
#pragma unroll
    for (int ti = 0; ti < SW / 16; ++ti) {   // 5 tiles
      floatx4 acc = {0.f, 0.f, 0.f, 0.f};
#pragma unroll
      for (int t = 0; t < 5; ++t) {
        const ushort_t* pf = rowp[t] + ti * 16 * CGP;
        const short4_t lo = *(const short4_t*)pf;
        const short4_t hi = *(const short4_t*)(pf + 4);
        const short8 bf = {lo[0], lo[1], lo[2], lo[3], hi[0], hi[1], hi[2], hi[3]};
        acc = __builtin_amdgcn_mfma_f32_16x16x32_bf16(bf, aw[t], acc, 0, 0, 0);  // A=x, B=w
      }
      floatx4 st = {acc[0] + bb, acc[1] + bb, acc[2] + bb, acc[3] + bb};
      __builtin_nontemporal_store(st, (floatx4*)(outb + ti * 16));  // nt (r13/r15 A/B)
    }
  };

  auto wrap6 = [](int v) { return v >= 6 ? v - 6 : v; };
  int m6 = (4 * q0 + 5) % 6;                 // slot of row rho = 4q-1 (ring-6)

  // ---- prologue: stage 6 rows ----
  {
    float ra[NP][4], rb[NP][4];
    LOADR(4 * q0 - 1, ra); LOADR(4 * q0 + 0, rb);
    CVTR(4 * q0 - 1, wrap6(m6 + 0), ra); CVTR(4 * q0 + 0, wrap6(m6 + 1), rb);
    LOADR(4 * q0 + 1, ra); LOADR(4 * q0 + 2, rb);
    CVTR(4 * q0 + 1, wrap6(m6 + 2), ra); CVTR(4 * q0 + 2, wrap6(m6 + 3), rb);
    LOADR(4 * q0 + 3, ra); LOADR(4 * q0 + 4, rb);
    CVTR(4 * q0 + 3, wrap6(m6 + 4), ra); CVTR(4 * q0 + 4, wrap6(m6 + 5), rb);
  }
  barrier_lgkm();

  // ---- task loop: straight-line body; final iteration peeled ----
#pragma unroll 1
  for (int q = q0; q < qend - 1; ++q) {
    float ra[NP][4], rb[NP][4], rc[NP][4], rd[NP][4];
    LOADR(4 * q + 5, ra); LOADR(4 * q + 6, rb);
    LOADR(4 * q + 7, rc); LOADR(4 * q + 8, rd);
    COMPUTE(q, m6);                          // prefetch drains under this
    barrier_lgkm();                          // tile readers done (lgkm only)
    CVTR(4 * q + 5, m6,            ra);
    CVTR(4 * q + 6, wrap6(m6 + 1), rb);
    CVTR(4 * q + 7, wrap6(m6 + 2), rc);
    CVTR(4 * q + 8, wrap6(m6 + 3), rd);
    barrier_lgkm();                          // tile ready for next task
    m6 = wrap6(m6 + 4);
  }
  COMPUTE(qend - 1, m6);                     // epilogue: no staging
}

extern "C" __global__ void __launch_bounds__(256, 5) conv_all(
    const float* __restrict__ x, const float* __restrict__ wgt,
    const float* __restrict__ bias, float* __restrict__ out) {
  extern __shared__ ushort_t lds[];
  // Balanced XCD map: xcd = bid&7 = batch; j = bid>>3 indexes the batch's 216
  // blocks ordered [G3(72) | G2(48) | G1(48) | G0(48)], each [strip][r][chunk].
  const int bid = blockIdx.x;
  const int b = bid & 7;
  const int j = bid >> 3;
  if (j < 72)       conv_group<3>(x, wgt, bias, out, lds, b, j);        // 4*18*1
  else if (j < 120) conv_group<2>(x, wgt, bias, out, lds, b, j - 72);   // 4*12*1
  else if (j < 168) conv_group<1>(x, wgt, bias, out, lds, b, j - 120);  // 4*6*2
  else              conv_group<0>(x, wgt, bias, out, lds, b, j - 168);  // 4*1*12
}

extern "C" void kernel_launch(void* const* d_in, const int* in_sizes, int n_in,
                              void* d_out, int out_size, void* d_ws, size_t ws_size,
                              hipStream_t stream) {
  const float* x    = (const float*)d_in[0];
  const float* wgt  = (const float*)d_in[1];
  const float* bias = (const float*)d_in[2];
  float* out        = (float*)d_out;

  // dynamic LDS (max over groups, G3): 6 * 116 * 20 * 2 = 27840 B -> 5 blocks/CU
  const size_t lds_bytes = (size_t)6 * 116 * CGP * 2;
  conv_all<<<dim3(1728), dim3(256), lds_bytes, stream>>>(x, wgt, bias, out);
}

// Round 19
// 97.094 us; speedup vs baseline: 1.1003x; 1.1003x over previous
//
#include <hip/hip_runtime.h>
#include <hip/hip_bf16.h>

typedef short short8 __attribute__((ext_vector_type(8)));
typedef short short4_t __attribute__((ext_vector_type(4)));
typedef float floatx4 __attribute__((ext_vector_type(4)));
typedef unsigned short ushort_t;
typedef unsigned int uint32;

#define H 320
#define W 320
#define CG 16
#define NCH 64
#define HW (H * W)
#define CGP 20       // ushorts per LDS col (40B): conflict-free frag reads (measured 0)
#define HALFW 160

__device__ __forceinline__ ushort_t f2bf(float f) {
  unsigned u = __float_as_uint(f);
  return (ushort_t)((u + 0x7FFFu + ((u >> 16) & 1u)) >> 16);  // RNE (weights only)
}

// LDS-only barrier: does NOT drain vmcnt -> global loads/stores stay in flight.
__device__ __forceinline__ void barrier_lgkm() {
  asm volatile("s_waitcnt lgkmcnt(0)" ::: "memory");
  __builtin_amdgcn_s_barrier();
}

// r19 = r17 (best: swapped MFMA + nt store + ring-6 + balanced XCD map) with a
// PAIRED-TILE epilogue: compute acc for ti=2t,2t+1 (two 64-B halves of the
// same 128-B line per oc-row), then issue both nt dwordx4 stores back-to-back
// so the store path can combine them into full-line HBM writes (kills the
// 237-vs-205MB nt partial-line inflation seen since r13).
template<int G>
__device__ __forceinline__ void conv_group(
    const float* __restrict__ x, const float* __restrict__ wgt,
    const float* __restrict__ bias, float* __restrict__ out,
    ushort_t* lds, int b, int bx) {
  constexpr int DIL   = (G == 0) ? 1 : (G == 1) ? 6 : (G == 2) ? 12 : 18;
  constexpr int KOFF  = DIL & 1;
  constexpr int SHIFT = DIL + KOFF;              // lds col c <-> global col wb + c - SHIFT
  constexpr int WH    = (HALFW + 2 * DIL + KOFF + 1) & ~1;  // 164/172/184/196
  constexpr int NP    = (WH + 63) / 64;          // 3/3/3/4
  constexpr int RPW   = (H + DIL - 1) / DIL;
  constexpr int Q     = (RPW + 3) / 4;           // 80/14/7/5 tasks per walk
  constexpr int CPW   = (G == 0) ? 12 : (G == 1) ? 2 : 1;
  constexpr int L     = (Q + CPW - 1) / CPW;     // 7/7/7/5 tasks per chunk

  const int tid = threadIdx.x;
  ushort_t* tile = lds;                          // [6][WH][CGP]
  ushort_t* swt  = lds + 6 * WH * CGP;           // [5][4][16][8] w-frag table
  uint32* swt32  = (uint32*)swt;

  // ---- weight fragment table (once per block) ----
#pragma unroll
  for (int k = 0; k < 5; ++k) {
    const int s = tid + k * 256;
    const int jp = s & 3, oc = (s >> 2) & 15, zz = (s >> 6) & 3, t = s >> 8;
    const int tp = 2 * t + (zz >> 1);
    uint32 pk = 0;
    if (tp < 9) {
      const float* wp = wgt + ((size_t)(G * CG + oc) * CG + (zz & 1) * 8 + 2 * jp) * 9 + tp;
      pk = (uint32)f2bf(wp[0]) | ((uint32)f2bf(wp[9]) << 16);
    }
    swt32[s] = pk;
  }
  __syncthreads();

  const int lane = tid & 63;
  const int wv   = tid >> 6;
  const int z = lane >> 4, icq = z & 1, pxl = lane & 15;
  short8 aw[5];
#pragma unroll
  for (int t = 0; t < 5; ++t) aw[t] = *(const short8*)&swt[((t * 4 + z) * 16 + pxl) * 8];
  const float bb = bias[G * CG + pxl];           // oc = lane&15 in swapped layout

  // ---- decode group-local bx -> (wb, r, chunk); b passed in (= XCD) ----
  const int chunk = bx % CPW;
  const int t1 = bx / CPW;
  const int r  = t1 % DIL;
  const int wb = (t1 / DIL) * HALFW;             // t1/DIL in {0,1}
  const int q0 = chunk * L;
  const int qend = (q0 + L < Q) ? q0 + L : Q;

  // ---- staging constants: thread = (col = lane, ch-quad = wv) ----
  bool zm[NP]; bool inb[NP]; int gofs[NP];
#pragma unroll
  for (int p = 0; p < NP; ++p) {
    const int c = 64 * p + lane;
    inb[p] = (c < WH);
    const int gc = wb + c - SHIFT;
    zm[p] = inb[p] & (gc >= 0) & (gc < W);
    gofs[p] = gc < 0 ? 0 : (gc >= W ? W - 1 : gc);
  }
  const float* chb = x + (size_t)(b * NCH + G * CG + 4 * wv) * HW;

  auto LOADR = [&](int rho, float (&rg)[NP][4]) {
    const int yy = rho * DIL + r;
    const int yyc = yy < 0 ? 0 : (yy >= H ? H - 1 : yy);
    const float* rp = chb + (size_t)yyc * W;
#pragma unroll
    for (int p = 0; p < NP; ++p)
#pragma unroll
      for (int k = 0; k < 4; ++k)
        rg[p][k] = rp[(size_t)k * HW + gofs[p]];   // 256B coalesced per inst
  };

  auto CVTR = [&](int rho, int slot, float (&rg)[NP][4]) {
    const int yy = rho * DIL + r;
    const bool rv = (yy >= 0) & (yy < H);
#pragma unroll
    for (int p = 0; p < NP; ++p) {
      const bool m = rv & zm[p];
      const __hip_bfloat162 h01 = __float22bfloat162_rn(make_float2(rg[p][0], rg[p][1]));
      const __hip_bfloat162 h23 = __float22bfloat162_rn(make_float2(rg[p][2], rg[p][3]));
      uint2 pk;
      pk.x = m ? *(const uint32*)&h01 : 0u;
      pk.y = m ? *(const uint32*)&h23 : 0u;
      if (inb[p]) {
        const int c = 64 * p + lane;
        *(uint2*)&tile[(size_t)(slot * WH + c) * CGP + wv * 4] = pk;  // ds_write_b64
      }
    }
  };

  auto COMPUTE = [&](int q, int m6) {
    const int y = (4 * q + wv) * DIL + r;
    if (y >= H) return;
    const int zh = z >> 1;
    // swapped C/D: lane&15 = oc, regs = px {4z..4z+3}
    float* outb = out + (size_t)(b * NCH + G * CG + pxl) * HW + (size_t)y * W + wb + 4 * z;
    const ushort_t* rowp[5];                 // statically indexed (unrolled t)
#pragma unroll
    for (int t = 0; t < 5; ++t) {
      const int tp = 2 * t + zh;
      const int ky = tp < 9 ? tp / 3 : 0;
      const int kx = tp < 9 ? tp - ky * 3 : 0;
      int s = m6 + wv + ky; s -= (s >= 6) ? 6 : 0;   // slot of row j = wv+ky
      rowp[t] = tile + (size_t)s * (WH * CGP) + (size_t)(pxl + kx * DIL + KOFF) * CGP + icq * 8;
    }
#pragma unroll 1
    for (int tj = 0; tj < HALFW / 32; ++tj) {      // tile PAIRS (128B per oc-row)
      floatx4 a0 = {0.f, 0.f, 0.f, 0.f};
      floatx4 a1 = {0.f, 0.f, 0.f, 0.f};
#pragma unroll
      for (int t = 0; t < 5; ++t) {
        const ushort_t* pf0 = rowp[t] + (2 * tj) * 16 * CGP;
        const short4_t lo0 = *(const short4_t*)pf0;
        const short4_t hi0 = *(const short4_t*)(pf0 + 4);
        const short8 bf0 = {lo0[0], lo0[1], lo0[2], lo0[3], hi0[0], hi0[1], hi0[2], hi0[3]};
        a0 = __builtin_amdgcn_mfma_f32_16x16x32_bf16(bf0, aw[t], a0, 0, 0, 0);
      }
#pragma unroll
      for (int t = 0; t < 5; ++t) {
        const ushort_t* pf1 = rowp[t] + (2 * tj + 1) * 16 * CGP;
        const short4_t lo1 = *(const short4_t*)pf1;
        const short4_t hi1 = *(const short4_t*)(pf1 + 4);
        const short8 bf1 = {lo1[0], lo1[1], lo1[2], lo1[3], hi1[0], hi1[1], hi1[2], hi1[3]};
        a1 = __builtin_amdgcn_mfma_f32_16x16x32_bf16(bf1, aw[t], a1, 0, 0, 0);
      }
      const floatx4 s0 = {a0[0] + bb, a0[1] + bb, a0[2] + bb, a0[3] + bb};
      const floatx4 s1 = {a1[0] + bb, a1[1] + bb, a1[2] + bb, a1[3] + bb};
      // adjacent 64-B halves of one 128-B line per oc-row, issued back-to-back
      __builtin_nontemporal_store(s0, (floatx4*)(outb + tj * 32));
      __builtin_nontemporal_store(s1, (floatx4*)(outb + tj * 32 + 16));
    }
  };

  auto wrap6 = [](int v) { return v >= 6 ? v - 6 : v; };
  int m6 = (4 * q0 + 5) % 6;                 // slot of row rho = 4q-1 (ring-6)

  // ---- prologue: stage 6 rows ----
  {
    float ra[NP][4], rb[NP][4];
    LOADR(4 * q0 - 1, ra); LOADR(4 * q0 + 0, rb);
    CVTR(4 * q0 - 1, wrap6(m6 + 0), ra); CVTR(4 * q0 + 0, wrap6(m6 + 1), rb);
    LOADR(4 * q0 + 1, ra); LOADR(4 * q0 + 2, rb);
    CVTR(4 * q0 + 1, wrap6(m6 + 2), ra); CVTR(4 * q0 + 2, wrap6(m6 + 3), rb);
    LOADR(4 * q0 + 3, ra); LOADR(4 * q0 + 4, rb);
    CVTR(4 * q0 + 3, wrap6(m6 + 4), ra); CVTR(4 * q0 + 4, wrap6(m6 + 5), rb);
  }
  barrier_lgkm();

  // ---- task loop: straight-line body; final iteration peeled ----
#pragma unroll 1
  for (int q = q0; q < qend - 1; ++q) {
    float ra[NP][4], rb[NP][4], rc[NP][4], rd[NP][4];
    LOADR(4 * q + 5, ra); LOADR(4 * q + 6, rb);
    LOADR(4 * q + 7, rc); LOADR(4 * q + 8, rd);
    COMPUTE(q, m6);                          // prefetch drains under this
    barrier_lgkm();                          // tile readers done (lgkm only)
    CVTR(4 * q + 5, m6,            ra);
    CVTR(4 * q + 6, wrap6(m6 + 1), rb);
    CVTR(4 * q + 7, wrap6(m6 + 2), rc);
    CVTR(4 * q + 8, wrap6(m6 + 3), rd);
    barrier_lgkm();                          // tile ready for next task
    m6 = wrap6(m6 + 4);
  }
  COMPUTE(qend - 1, m6);                     // epilogue: no staging
}

extern "C" __global__ void __launch_bounds__(256, 3) conv_all(
    const float* __restrict__ x, const float* __restrict__ wgt,
    const float* __restrict__ bias, float* __restrict__ out) {
  extern __shared__ ushort_t lds[];
  // Balanced XCD map: xcd = bid&7 = batch; j = bid>>3 indexes the batch's 108
  // blocks ordered [G3(36) | G2(24) | G1(24) | G0(24)], each [wb][r][chunk].
  const int bid = blockIdx.x;
  const int b = bid & 7;
  const int j = bid >> 3;
  if (j < 36)      conv_group<3>(x, wgt, bias, out, lds, b, j);       // 2*18*1
  else if (j < 60) conv_group<2>(x, wgt, bias, out, lds, b, j - 36);  // 2*12*1
  else if (j < 84) conv_group<1>(x, wgt, bias, out, lds, b, j - 60);  // 2*6*2
  else             conv_group<0>(x, wgt, bias, out, lds, b, j - 84);  // 2*1*12
}

extern "C" void kernel_launch(void* const* d_in, const int* in_sizes, int n_in,
                              void* d_out, int out_size, void* d_ws, size_t ws_size,
                              hipStream_t stream) {
  const float* x    = (const float*)d_in[0];
  const float* wgt  = (const float*)d_in[1];
  const float* bias = (const float*)d_in[2];
  float* out        = (float*)d_out;

  // dynamic LDS (max over groups, G3): 6*196*20*2 + 5120 = 52160 B -> 3 blocks/CU
  const size_t lds_bytes = (size_t)(6 * 196 * CGP + 5 * 4 * 16 * 8) * 2;
  conv_all<<<dim3(864), dim3(256), lds_bytes, stream>>>(x, wgt, bias, out);
}